// Round 8
// baseline (455.241 us; speedup 1.0000x reference)
//
#include <hip/hip_runtime.h>
#include <hip/hip_bf16.h>

#define N_NODES   50000
#define N_EDGES   500000
#define FDIM      128
#define N_CLASSES 32
#define N_GRAPHS  64

// ---------------------------------------------------------------------------
// Preprocessing: degree count, prefix scan over PADDED degrees (pad to x4),
// CSR fill + dummy self-edge padding (w=0) to kill the serial gather tail.
// ---------------------------------------------------------------------------

__global__ void deg_kernel(const int* __restrict__ dst, int* __restrict__ deg, int E) {
    int e = blockIdx.x * blockDim.x + threadIdx.x;
    if (e < E) atomicAdd(&deg[dst[e]], 1);
}

// scan over padded degree (deg+3)&~3; also computes dis[] (fused)
__global__ void scan_partial(const int* __restrict__ deg, int* __restrict__ part,
                             float* __restrict__ dis, int n) {
    __shared__ int s[512];
    int t = threadIdx.x;
    int i = blockIdx.x * 512 + t;
    int d = (i < n) ? deg[i] : 0;
    if (i < n) dis[i] = rsqrtf((float)d + 1.0f);
    s[t] = (i < n) ? ((d + 3) & ~3) : 0;
    __syncthreads();
    for (int o = 256; o > 0; o >>= 1) {
        if (t < o) s[t] += s[t + o];
        __syncthreads();
    }
    if (t == 0) part[blockIdx.x] = s[0];
}

__global__ void scan_offsets(int* part, int nb) {
    if (blockIdx.x == 0 && threadIdx.x == 0) {
        int acc = 0;
        for (int i = 0; i < nb; i++) { int v = part[i]; part[i] = acc; acc += v; }
    }
}

__global__ void scan_final(const int* __restrict__ deg, const int* __restrict__ part,
                           int* __restrict__ rowptr, int n) {
    __shared__ int s[512];
    int t = threadIdx.x;
    int i = blockIdx.x * 512 + t;
    int v = (i < n) ? ((deg[i] + 3) & ~3) : 0;
    s[t] = v;
    __syncthreads();
    for (int o = 1; o < 512; o <<= 1) {
        int x = (t >= o) ? s[t - o] : 0;
        __syncthreads();
        s[t] += x;
        __syncthreads();
    }
    if (i < n) rowptr[i] = part[blockIdx.x] + s[t] - v;   // exclusive (padded)
}

__global__ void fill_csr(const int* __restrict__ src, const int* __restrict__ dst,
                         const int* __restrict__ rowptr, int* __restrict__ fill,
                         const float* __restrict__ dis,
                         int2* __restrict__ csr_sw, int E) {
    int e = blockIdx.x * blockDim.x + threadIdx.x;
    if (e >= E) return;
    int d = dst[e], s = src[e];
    int pos = rowptr[d] + atomicAdd(&fill[d], 1);
    float w = dis[s] * dis[d];
    csr_sw[pos] = make_int2(s, __float_as_int(w));
}

// fill pad slots [deg, (deg+3)&~3) with (v, w=0): exact no-op edges that hit
// the node's own (cached) row -> all agg batches are 4/8-deep, no serial tail
__global__ void pad_csr(const int* __restrict__ deg, const int* __restrict__ rowptr,
                        int2* __restrict__ csr_sw, int n) {
    int v = blockIdx.x * blockDim.x + threadIdx.x;
    if (v >= n) return;
    int d = deg[v], dp = (d + 3) & ~3;
    int base = rowptr[v];
    for (int i = d; i < dp; i++) csr_sw[base + i] = make_int2(v, 0);
}

// ---------------------------------------------------------------------------
// GEMM: H[n][128] = X[n][128] @ W[128][128]
// 64x128 tile, 256 threads, 8x4 micro-tile (48B LDS / 32 FMA = 1.5 B/FMA)
// 782 blocks -> ~3 blocks/CU (LDS 25.6KB/block), both LDS reads conflict-free
// ---------------------------------------------------------------------------

__global__ __launch_bounds__(256) void gemm64(const float* __restrict__ X,
                                              const float* __restrict__ W,
                                              float* __restrict__ H, int n) {
    __shared__ __align__(16) float xs[32][68];   // xs[k][row], 64 rows + pad
    __shared__ __align__(16) float ws[32][132];  // ws[k][col]
    int t = threadIdx.x;
    int ti = t & 7;      // row group: rows ti*8 .. ti*8+7
    int tj = t >> 3;     // col group: cols tj*4 .. tj*4+3
    int rowBase = blockIdx.x * 64;

    float acc[8][4];
#pragma unroll
    for (int r = 0; r < 8; r++)
#pragma unroll
        for (int c = 0; c < 4; c++) acc[r][c] = 0.f;

    for (int k0 = 0; k0 < 128; k0 += 32) {
        __syncthreads();
        // stage X transposed: two float4 per thread (rows 0-31, 32-63)
        {
            int kq = t & 7;
#pragma unroll
            for (int p = 0; p < 2; p++) {
                int r = (t >> 3) + 32 * p;
                int grow = rowBase + r;
                float4 v = make_float4(0.f, 0.f, 0.f, 0.f);
                if (grow < n) v = *(const float4*)(X + (size_t)grow * FDIM + k0 + kq * 4);
                xs[kq * 4 + 0][r] = v.x;
                xs[kq * 4 + 1][r] = v.y;
                xs[kq * 4 + 2][r] = v.z;
                xs[kq * 4 + 3][r] = v.w;
            }
        }
        // stage W natural layout: 4 float4 per thread
        {
            int c4 = t & 31, kr = t >> 5;
#pragma unroll
            for (int p = 0; p < 4; p++) {
                int k = kr + 8 * p;
                float4 v = *(const float4*)(W + (size_t)(k0 + k) * FDIM + c4 * 4);
                *(float4*)&ws[k][c4 * 4] = v;
            }
        }
        __syncthreads();
#pragma unroll 8
        for (int k = 0; k < 32; k++) {
            float4 a0 = *(const float4*)&xs[k][ti * 8];
            float4 a1 = *(const float4*)&xs[k][ti * 8 + 4];
            float4 b = *(const float4*)&ws[k][tj * 4];
            float ar[8] = {a0.x, a0.y, a0.z, a0.w, a1.x, a1.y, a1.z, a1.w};
            float br[4] = {b.x, b.y, b.z, b.w};
#pragma unroll
            for (int r = 0; r < 8; r++)
#pragma unroll
                for (int c = 0; c < 4; c++) acc[r][c] = fmaf(ar[r], br[c], acc[r][c]);
        }
    }

#pragma unroll
    for (int rr = 0; rr < 8; rr++) {
        int grow = rowBase + ti * 8 + rr;
        if (grow < n) {
            float4 o = {acc[rr][0], acc[rr][1], acc[rr][2], acc[rr][3]};
            *(float4*)(H + (size_t)grow * FDIM + tj * 4) = o;
        }
    }
}

// ---------------------------------------------------------------------------
// Aggregate: OUT[v] = sum_e w_e*H[src_e] + (1/deg)*H[v] + b (+ReLU)
// One wave per node; padded edge count (x4) -> only 8/4-deep batches.
// ---------------------------------------------------------------------------

__global__ __launch_bounds__(256) void agg_kernel(const float* __restrict__ H,
                                                  float* __restrict__ OUT,
                                                  const int* __restrict__ rowptr,
                                                  const int* __restrict__ degi,
                                                  const int2* __restrict__ csr_sw,
                                                  const float* __restrict__ dis,
                                                  const float* __restrict__ bias,
                                                  int n, int relu) {
    int wid = (blockIdx.x * blockDim.x + threadIdx.x) >> 6;
    int lane = threadIdx.x & 63;
    if (wid >= n) return;
    int v = wid;
    const int2* sw = csr_sw + rowptr[v];
    int cnt = (degi[v] + 3) & ~3;   // padded
    float ax = 0.f, ay = 0.f;
    int e = 0;

    for (; e + 8 <= cnt; e += 8) {
        int2 p0 = sw[e + 0], p1 = sw[e + 1], p2 = sw[e + 2], p3 = sw[e + 3];
        int2 p4 = sw[e + 4], p5 = sw[e + 5], p6 = sw[e + 6], p7 = sw[e + 7];
        float2 m0 = *(const float2*)(H + (size_t)p0.x * FDIM + lane * 2);
        float2 m1 = *(const float2*)(H + (size_t)p1.x * FDIM + lane * 2);
        float2 m2 = *(const float2*)(H + (size_t)p2.x * FDIM + lane * 2);
        float2 m3 = *(const float2*)(H + (size_t)p3.x * FDIM + lane * 2);
        float2 m4 = *(const float2*)(H + (size_t)p4.x * FDIM + lane * 2);
        float2 m5 = *(const float2*)(H + (size_t)p5.x * FDIM + lane * 2);
        float2 m6 = *(const float2*)(H + (size_t)p6.x * FDIM + lane * 2);
        float2 m7 = *(const float2*)(H + (size_t)p7.x * FDIM + lane * 2);
        ax = fmaf(__int_as_float(p0.y), m0.x, ax); ay = fmaf(__int_as_float(p0.y), m0.y, ay);
        ax = fmaf(__int_as_float(p1.y), m1.x, ax); ay = fmaf(__int_as_float(p1.y), m1.y, ay);
        ax = fmaf(__int_as_float(p2.y), m2.x, ax); ay = fmaf(__int_as_float(p2.y), m2.y, ay);
        ax = fmaf(__int_as_float(p3.y), m3.x, ax); ay = fmaf(__int_as_float(p3.y), m3.y, ay);
        ax = fmaf(__int_as_float(p4.y), m4.x, ax); ay = fmaf(__int_as_float(p4.y), m4.y, ay);
        ax = fmaf(__int_as_float(p5.y), m5.x, ax); ay = fmaf(__int_as_float(p5.y), m5.y, ay);
        ax = fmaf(__int_as_float(p6.y), m6.x, ax); ay = fmaf(__int_as_float(p6.y), m6.y, ay);
        ax = fmaf(__int_as_float(p7.y), m7.x, ax); ay = fmaf(__int_as_float(p7.y), m7.y, ay);
    }
    if (e + 4 <= cnt) {
        int2 p0 = sw[e + 0], p1 = sw[e + 1], p2 = sw[e + 2], p3 = sw[e + 3];
        float2 m0 = *(const float2*)(H + (size_t)p0.x * FDIM + lane * 2);
        float2 m1 = *(const float2*)(H + (size_t)p1.x * FDIM + lane * 2);
        float2 m2 = *(const float2*)(H + (size_t)p2.x * FDIM + lane * 2);
        float2 m3 = *(const float2*)(H + (size_t)p3.x * FDIM + lane * 2);
        ax = fmaf(__int_as_float(p0.y), m0.x, ax); ay = fmaf(__int_as_float(p0.y), m0.y, ay);
        ax = fmaf(__int_as_float(p1.y), m1.x, ax); ay = fmaf(__int_as_float(p1.y), m1.y, ay);
        ax = fmaf(__int_as_float(p2.y), m2.x, ax); ay = fmaf(__int_as_float(p2.y), m2.y, ay);
        ax = fmaf(__int_as_float(p3.y), m3.x, ax); ay = fmaf(__int_as_float(p3.y), m3.y, ay);
    }

    float dv = dis[v];
    float ns = dv * dv;
    float2 hv = *(const float2*)(H + (size_t)v * FDIM + lane * 2);
    float2 bb = *(const float2*)(bias + lane * 2);
    float ox = ax + ns * hv.x + bb.x;
    float oy = ay + ns * hv.y + bb.y;
    if (relu) { ox = fmaxf(ox, 0.f); oy = fmaxf(oy, 0.f); }
    *(float2*)(OUT + (size_t)v * FDIM + lane * 2) = make_float2(ox, oy);
}

// ---------------------------------------------------------------------------
// Pooling: batch[] is SORTED. Each 128-thread block owns a contiguous node
// chunk; thread t owns feature t; flush one atomic per graph-boundary.
// ---------------------------------------------------------------------------

#define POOL_BLOCKS 1024

__global__ __launch_bounds__(128) void pool_kernel(const float* __restrict__ H,
                                                   const int* __restrict__ batch,
                                                   float* __restrict__ psum,
                                                   float* __restrict__ pcnt, int n) {
    int t = threadIdx.x;  // feature index 0..127
    int chunk = (n + POOL_BLOCKS - 1) / POOL_BLOCKS;
    int lo = blockIdx.x * chunk;
    int hi = lo + chunk; if (hi > n) hi = n;
    if (lo >= hi) return;

    float acc = 0.f;
    int cnt = 0;
    int curg = batch[lo];
    float hv = H[(size_t)lo * FDIM + t];
    int g = curg;
    for (int v = lo; v < hi; v++) {
        float hcur = hv;
        int gcur = g;
        if (v + 1 < hi) {
            hv = H[(size_t)(v + 1) * FDIM + t];
            g = batch[v + 1];
        }
        if (gcur != curg) {
            atomicAdd(&psum[curg * FDIM + t], acc);
            if (t == 0) atomicAdd(&pcnt[curg], (float)cnt);
            acc = 0.f; cnt = 0; curg = gcur;
        }
        acc += hcur;
        cnt++;
    }
    atomicAdd(&psum[curg * FDIM + t], acc);
    if (t == 0) atomicAdd(&pcnt[curg], (float)cnt);
}

__global__ void final_lin(const float* __restrict__ psum, const float* __restrict__ pcnt,
                          const float* __restrict__ Wl, const float* __restrict__ bl,
                          float* __restrict__ out) {
    int t = blockIdx.x * blockDim.x + threadIdx.x;
    if (t >= N_GRAPHS * N_CLASSES) return;
    int g = t >> 5, c = t & 31;
    float inv = 1.0f / fmaxf(pcnt[g], 1.0f);
    float s = 0.f;
    for (int k = 0; k < FDIM; k++) s = fmaf(psum[g * FDIM + k], Wl[k * N_CLASSES + c], s);
    out[t] = s * inv + bl[c];
}

// ---------------------------------------------------------------------------

static inline size_t align256(size_t x) { return (x + 255) & ~(size_t)255; }

extern "C" void kernel_launch(void* const* d_in, const int* in_sizes, int n_in,
                              void* d_out, int out_size, void* d_ws, size_t ws_size,
                              hipStream_t stream) {
    const float* x     = (const float*)d_in[0];
    const int*   ei    = (const int*)d_in[1];
    const int*   batch = (const int*)d_in[2];
    const float* Wls[5] = {(const float*)d_in[3], (const float*)d_in[5], (const float*)d_in[7],
                           (const float*)d_in[9], (const float*)d_in[11]};
    const float* bls[5] = {(const float*)d_in[4], (const float*)d_in[6], (const float*)d_in[8],
                           (const float*)d_in[10], (const float*)d_in[12]};
    const float* W_lin = (const float*)d_in[13];
    const float* b_lin = (const float*)d_in[14];
    float* out = (float*)d_out;

    const int N = N_NODES, E = N_EDGES;
    const int* src = ei;
    const int* dst = ei + E;

    // workspace layout: zeroed arrays (deg,fill,psum,pcnt) laid out contiguously
    char* p = (char*)d_ws;
    size_t off = 0;
    float* hA = (float*)(p + off); off = align256(off + (size_t)N * FDIM * 4);
    float* hB = (float*)(p + off); off = align256(off + (size_t)N * FDIM * 4);
    int2*  csr_sw = (int2*)(p + off); off = align256(off + ((size_t)E + 4 * N) * 8);
    float* dis = (float*)(p + off); off = align256(off + (size_t)N * 4);
    int*   rowptr = (int*)(p + off); off = align256(off + (size_t)N * 4);
    int*   part = (int*)(p + off); off = align256(off + 512);
    size_t zero_off = off;
    int*   deg = (int*)(p + off); off = align256(off + (size_t)N * 4);
    int*   fill = (int*)(p + off); off = align256(off + (size_t)N * 4);
    float* psum = (float*)(p + off); off = align256(off + (size_t)N_GRAPHS * FDIM * 4);
    float* pcnt = (float*)(p + off); off = align256(off + (size_t)N_GRAPHS * 4);
    size_t zero_bytes = off - zero_off;
    (void)ws_size; (void)n_in; (void)in_sizes; (void)out_size;

    // single fused zero of all accumulators
    hipMemsetAsync(p + zero_off, 0, zero_bytes, stream);

    // preprocessing
    deg_kernel<<<(E + 255) / 256, 256, 0, stream>>>(dst, deg, E);
    int nChunks = (N + 511) / 512;  // 98
    scan_partial<<<nChunks, 512, 0, stream>>>(deg, part, dis, N);
    scan_offsets<<<1, 64, 0, stream>>>(part, nChunks);
    scan_final<<<nChunks, 512, 0, stream>>>(deg, part, rowptr, N);
    fill_csr<<<(E + 255) / 256, 256, 0, stream>>>(src, dst, rowptr, fill, dis,
                                                  csr_sw, E);
    pad_csr<<<(N + 255) / 256, 256, 0, stream>>>(deg, rowptr, csr_sw, N);

    // 5 GCN layers, ping-pong hA/hB
    int gemmBlocks = (N + 63) / 64;          // 782
    int aggBlocks = (N * 64 + 255) / 256;    // 12500
    const float* cur = x;
    for (int l = 0; l < 5; l++) {
        gemm64<<<gemmBlocks, 256, 0, stream>>>(cur, Wls[l], hA, N);
        int relu = (l < 4) ? 1 : 0;
        agg_kernel<<<aggBlocks, 256, 0, stream>>>(hA, hB, rowptr, deg, csr_sw,
                                                  dis, bls[l], N, relu);
        cur = hB;
    }

    // pooling + classifier
    pool_kernel<<<POOL_BLOCKS, 128, 0, stream>>>(hB, batch, psum, pcnt, N);
    final_lin<<<(N_GRAPHS * N_CLASSES + 255) / 256, 256, 0, stream>>>(psum, pcnt, W_lin,
                                                                      b_lin, out);
}

// Round 9
// 450.152 us; speedup vs baseline: 1.0113x; 1.0113x over previous
//
#include <hip/hip_runtime.h>
#include <hip/hip_bf16.h>

#define N_NODES   50000
#define N_EDGES   500000
#define FDIM      128
#define N_CLASSES 32
#define N_GRAPHS  64

// ---------------------------------------------------------------------------
// Preprocessing: degree count, prefix scan over PADDED degrees (pad to x4),
// CSR fill + dummy self-edge padding (w=0).
// ---------------------------------------------------------------------------

__global__ void deg_kernel(const int* __restrict__ dst, int* __restrict__ deg, int E) {
    int e = blockIdx.x * blockDim.x + threadIdx.x;
    if (e < E) atomicAdd(&deg[dst[e]], 1);
}

// scan over padded degree (deg+3)&~3; also computes dis[] (fused)
__global__ void scan_partial(const int* __restrict__ deg, int* __restrict__ part,
                             float* __restrict__ dis, int n) {
    __shared__ int s[512];
    int t = threadIdx.x;
    int i = blockIdx.x * 512 + t;
    int d = (i < n) ? deg[i] : 0;
    if (i < n) dis[i] = rsqrtf((float)d + 1.0f);
    s[t] = (i < n) ? ((d + 3) & ~3) : 0;
    __syncthreads();
    for (int o = 256; o > 0; o >>= 1) {
        if (t < o) s[t] += s[t + o];
        __syncthreads();
    }
    if (t == 0) part[blockIdx.x] = s[0];
}

__global__ void scan_offsets(int* part, int nb) {
    if (blockIdx.x == 0 && threadIdx.x == 0) {
        int acc = 0;
        for (int i = 0; i < nb; i++) { int v = part[i]; part[i] = acc; acc += v; }
    }
}

__global__ void scan_final(const int* __restrict__ deg, const int* __restrict__ part,
                           int* __restrict__ rowptr, int n) {
    __shared__ int s[512];
    int t = threadIdx.x;
    int i = blockIdx.x * 512 + t;
    int v = (i < n) ? ((deg[i] + 3) & ~3) : 0;
    s[t] = v;
    __syncthreads();
    for (int o = 1; o < 512; o <<= 1) {
        int x = (t >= o) ? s[t - o] : 0;
        __syncthreads();
        s[t] += x;
        __syncthreads();
    }
    if (i < n) rowptr[i] = part[blockIdx.x] + s[t] - v;   // exclusive (padded)
}

__global__ void fill_csr(const int* __restrict__ src, const int* __restrict__ dst,
                         const int* __restrict__ rowptr, int* __restrict__ fill,
                         const float* __restrict__ dis,
                         int2* __restrict__ csr_sw, int E) {
    int e = blockIdx.x * blockDim.x + threadIdx.x;
    if (e >= E) return;
    int d = dst[e], s = src[e];
    int pos = rowptr[d] + atomicAdd(&fill[d], 1);
    float w = dis[s] * dis[d];
    csr_sw[pos] = make_int2(s, __float_as_int(w));
}

__global__ void pad_csr(const int* __restrict__ deg, const int* __restrict__ rowptr,
                        int2* __restrict__ csr_sw, int n) {
    int v = blockIdx.x * blockDim.x + threadIdx.x;
    if (v >= n) return;
    int d = deg[v], dp = (d + 3) & ~3;
    int base = rowptr[v];
    for (int i = d; i < dp; i++) csr_sw[base + i] = make_int2(v, 0);
}

// ---------------------------------------------------------------------------
// GEMM (R7-proven): 32x128 tile, 256 threads, 4x4 micro-tile
// ---------------------------------------------------------------------------

__global__ __launch_bounds__(256) void gemm32(const float* __restrict__ X,
                                              const float* __restrict__ W,
                                              float* __restrict__ H, int n) {
    __shared__ __align__(16) float xs[32][36];
    __shared__ __align__(16) float ws[32][132];
    int t = threadIdx.x;
    int ti = t & 7;
    int tj = t >> 3;
    int rowBase = blockIdx.x * 32;

    float acc[4][4];
#pragma unroll
    for (int r = 0; r < 4; r++)
#pragma unroll
        for (int c = 0; c < 4; c++) acc[r][c] = 0.f;

    for (int k0 = 0; k0 < 128; k0 += 32) {
        __syncthreads();
        {
            int r = t >> 3, kq = t & 7;
            int grow = rowBase + r;
            float4 v = make_float4(0.f, 0.f, 0.f, 0.f);
            if (grow < n) v = *(const float4*)(X + (size_t)grow * FDIM + k0 + kq * 4);
            xs[kq * 4 + 0][r] = v.x;
            xs[kq * 4 + 1][r] = v.y;
            xs[kq * 4 + 2][r] = v.z;
            xs[kq * 4 + 3][r] = v.w;
        }
        {
            int c4 = t & 31, kr = t >> 5;
#pragma unroll
            for (int p = 0; p < 4; p++) {
                int k = kr + 8 * p;
                float4 v = *(const float4*)(W + (size_t)(k0 + k) * FDIM + c4 * 4);
                *(float4*)&ws[k][c4 * 4] = v;
            }
        }
        __syncthreads();
#pragma unroll 8
        for (int k = 0; k < 32; k++) {
            float4 a = *(const float4*)&xs[k][ti * 4];
            float4 b = *(const float4*)&ws[k][tj * 4];
            float ar[4] = {a.x, a.y, a.z, a.w};
            float br[4] = {b.x, b.y, b.z, b.w};
#pragma unroll
            for (int r = 0; r < 4; r++)
#pragma unroll
                for (int c = 0; c < 4; c++) acc[r][c] = fmaf(ar[r], br[c], acc[r][c]);
        }
    }

#pragma unroll
    for (int rr = 0; rr < 4; rr++) {
        int grow = rowBase + ti * 4 + rr;
        if (grow < n) {
            float4 o = {acc[rr][0], acc[rr][1], acc[rr][2], acc[rr][3]};
            *(float4*)(H + (size_t)grow * FDIM + tj * 4) = o;
        }
    }
}

// ---------------------------------------------------------------------------
// Aggregate: OUT[v] = sum_e w_e*H[src_e] + (1/deg)*H[v] + b (+ReLU)
// One wave per node, float4/lane, 32 lanes per row -> each gather instruction
// services TWO edges (halves of the wave). 8 instrs in flight = 16 edges.
// Halves merged at the end via __shfl_xor(...,32).
// ---------------------------------------------------------------------------

#define PGATH(I, EBASE)                                                         \
    int2 p##I = sw[(EBASE) + 2 * (I) + half];                                   \
    float4 m##I = *(const float4*)(H + (size_t)p##I.x * FDIM + q * 4);

#define PFMA(I)                                                                 \
    {                                                                           \
        float w_ = __int_as_float(p##I.y);                                      \
        acc.x = fmaf(w_, m##I.x, acc.x);                                        \
        acc.y = fmaf(w_, m##I.y, acc.y);                                        \
        acc.z = fmaf(w_, m##I.z, acc.z);                                        \
        acc.w = fmaf(w_, m##I.w, acc.w);                                        \
    }

__global__ __launch_bounds__(256) void agg_kernel(const float* __restrict__ H,
                                                  float* __restrict__ OUT,
                                                  const int* __restrict__ rowptr,
                                                  const int* __restrict__ degi,
                                                  const int2* __restrict__ csr_sw,
                                                  const float* __restrict__ dis,
                                                  const float* __restrict__ bias,
                                                  int n, int relu) {
    int wid = (blockIdx.x * blockDim.x + threadIdx.x) >> 6;
    int lane = threadIdx.x & 63;
    if (wid >= n) return;
    int v = __builtin_amdgcn_readfirstlane(wid);   // wave-uniform -> scalar loads
    int half = lane >> 5;   // which edge of the pair
    int q = lane & 31;      // feature quarter: features q*4 .. q*4+3

    const int2* sw = csr_sw + rowptr[v];
    int cnt = (degi[v] + 3) & ~3;   // padded, multiple of 4
    float4 acc = make_float4(0.f, 0.f, 0.f, 0.f);
    int e = 0;

    for (; e + 16 <= cnt; e += 16) {   // 8 instructions, 16 edges
        PGATH(0, e) PGATH(1, e) PGATH(2, e) PGATH(3, e)
        PGATH(4, e) PGATH(5, e) PGATH(6, e) PGATH(7, e)
        PFMA(0) PFMA(1) PFMA(2) PFMA(3) PFMA(4) PFMA(5) PFMA(6) PFMA(7)
    }
    if (e + 8 <= cnt) {                // 4 instructions, 8 edges
        PGATH(0, e) PGATH(1, e) PGATH(2, e) PGATH(3, e)
        PFMA(0) PFMA(1) PFMA(2) PFMA(3)
        e += 8;
    }
    if (e + 4 <= cnt) {                // 2 instructions, 4 edges
        PGATH(0, e) PGATH(1, e)
        PFMA(0) PFMA(1)
    }

    // merge the two halves: lane and lane^32 hold complementary edge subsets
    acc.x += __shfl_xor(acc.x, 32);
    acc.y += __shfl_xor(acc.y, 32);
    acc.z += __shfl_xor(acc.z, 32);
    acc.w += __shfl_xor(acc.w, 32);

    if (half == 0) {
        float dv = dis[v];
        float ns = dv * dv;
        float4 hv = *(const float4*)(H + (size_t)v * FDIM + q * 4);
        float4 bb = *(const float4*)(bias + q * 4);
        float4 o;
        o.x = acc.x + ns * hv.x + bb.x;
        o.y = acc.y + ns * hv.y + bb.y;
        o.z = acc.z + ns * hv.z + bb.z;
        o.w = acc.w + ns * hv.w + bb.w;
        if (relu) {
            o.x = fmaxf(o.x, 0.f); o.y = fmaxf(o.y, 0.f);
            o.z = fmaxf(o.z, 0.f); o.w = fmaxf(o.w, 0.f);
        }
        *(float4*)(OUT + (size_t)v * FDIM + q * 4) = o;
    }
}

// ---------------------------------------------------------------------------
// Pooling: batch[] is SORTED. Segmented reduce, one atomic per boundary.
// ---------------------------------------------------------------------------

#define POOL_BLOCKS 1024

__global__ __launch_bounds__(128) void pool_kernel(const float* __restrict__ H,
                                                   const int* __restrict__ batch,
                                                   float* __restrict__ psum,
                                                   float* __restrict__ pcnt, int n) {
    int t = threadIdx.x;
    int chunk = (n + POOL_BLOCKS - 1) / POOL_BLOCKS;
    int lo = blockIdx.x * chunk;
    int hi = lo + chunk; if (hi > n) hi = n;
    if (lo >= hi) return;

    float acc = 0.f;
    int cnt = 0;
    int curg = batch[lo];
    float hv = H[(size_t)lo * FDIM + t];
    int g = curg;
    for (int v = lo; v < hi; v++) {
        float hcur = hv;
        int gcur = g;
        if (v + 1 < hi) {
            hv = H[(size_t)(v + 1) * FDIM + t];
            g = batch[v + 1];
        }
        if (gcur != curg) {
            atomicAdd(&psum[curg * FDIM + t], acc);
            if (t == 0) atomicAdd(&pcnt[curg], (float)cnt);
            acc = 0.f; cnt = 0; curg = gcur;
        }
        acc += hcur;
        cnt++;
    }
    atomicAdd(&psum[curg * FDIM + t], acc);
    if (t == 0) atomicAdd(&pcnt[curg], (float)cnt);
}

__global__ void final_lin(const float* __restrict__ psum, const float* __restrict__ pcnt,
                          const float* __restrict__ Wl, const float* __restrict__ bl,
                          float* __restrict__ out) {
    int t = blockIdx.x * blockDim.x + threadIdx.x;
    if (t >= N_GRAPHS * N_CLASSES) return;
    int g = t >> 5, c = t & 31;
    float inv = 1.0f / fmaxf(pcnt[g], 1.0f);
    float s = 0.f;
    for (int k = 0; k < FDIM; k++) s = fmaf(psum[g * FDIM + k], Wl[k * N_CLASSES + c], s);
    out[t] = s * inv + bl[c];
}

// ---------------------------------------------------------------------------

static inline size_t align256(size_t x) { return (x + 255) & ~(size_t)255; }

extern "C" void kernel_launch(void* const* d_in, const int* in_sizes, int n_in,
                              void* d_out, int out_size, void* d_ws, size_t ws_size,
                              hipStream_t stream) {
    const float* x     = (const float*)d_in[0];
    const int*   ei    = (const int*)d_in[1];
    const int*   batch = (const int*)d_in[2];
    const float* Wls[5] = {(const float*)d_in[3], (const float*)d_in[5], (const float*)d_in[7],
                           (const float*)d_in[9], (const float*)d_in[11]};
    const float* bls[5] = {(const float*)d_in[4], (const float*)d_in[6], (const float*)d_in[8],
                           (const float*)d_in[10], (const float*)d_in[12]};
    const float* W_lin = (const float*)d_in[13];
    const float* b_lin = (const float*)d_in[14];
    float* out = (float*)d_out;

    const int N = N_NODES, E = N_EDGES;
    const int* src = ei;
    const int* dst = ei + E;

    // workspace layout: zeroed arrays (deg,fill,psum,pcnt) laid out contiguously
    char* p = (char*)d_ws;
    size_t off = 0;
    float* hA = (float*)(p + off); off = align256(off + (size_t)N * FDIM * 4);
    float* hB = (float*)(p + off); off = align256(off + (size_t)N * FDIM * 4);
    int2*  csr_sw = (int2*)(p + off); off = align256(off + ((size_t)E + 4 * N) * 8);
    float* dis = (float*)(p + off); off = align256(off + (size_t)N * 4);
    int*   rowptr = (int*)(p + off); off = align256(off + (size_t)N * 4);
    int*   part = (int*)(p + off); off = align256(off + 512);
    size_t zero_off = off;
    int*   deg = (int*)(p + off); off = align256(off + (size_t)N * 4);
    int*   fill = (int*)(p + off); off = align256(off + (size_t)N * 4);
    float* psum = (float*)(p + off); off = align256(off + (size_t)N_GRAPHS * FDIM * 4);
    float* pcnt = (float*)(p + off); off = align256(off + (size_t)N_GRAPHS * 4);
    size_t zero_bytes = off - zero_off;
    (void)ws_size; (void)n_in; (void)in_sizes; (void)out_size;

    hipMemsetAsync(p + zero_off, 0, zero_bytes, stream);

    // preprocessing
    deg_kernel<<<(E + 255) / 256, 256, 0, stream>>>(dst, deg, E);
    int nChunks = (N + 511) / 512;  // 98
    scan_partial<<<nChunks, 512, 0, stream>>>(deg, part, dis, N);
    scan_offsets<<<1, 64, 0, stream>>>(part, nChunks);
    scan_final<<<nChunks, 512, 0, stream>>>(deg, part, rowptr, N);
    fill_csr<<<(E + 255) / 256, 256, 0, stream>>>(src, dst, rowptr, fill, dis,
                                                  csr_sw, E);
    pad_csr<<<(N + 255) / 256, 256, 0, stream>>>(deg, rowptr, csr_sw, N);

    // 5 GCN layers, ping-pong hA/hB
    int gemmBlocks = (N + 31) / 32;          // 1563
    int aggBlocks = (N * 64 + 255) / 256;    // 12500
    const float* cur = x;
    for (int l = 0; l < 5; l++) {
        gemm32<<<gemmBlocks, 256, 0, stream>>>(cur, Wls[l], hA, N);
        int relu = (l < 4) ? 1 : 0;
        agg_kernel<<<aggBlocks, 256, 0, stream>>>(hA, hB, rowptr, deg, csr_sw,
                                                  dis, bls[l], N, relu);
        cur = hB;
    }

    // pooling + classifier
    pool_kernel<<<POOL_BLOCKS, 128, 0, stream>>>(hB, batch, psum, pcnt, N);
    final_lin<<<(N_GRAPHS * N_CLASSES + 255) / 256, 256, 0, stream>>>(psum, pcnt, W_lin,
                                                                      b_lin, out);
}

// Round 10
// 419.683 us; speedup vs baseline: 1.0847x; 1.0726x over previous
//
#include <hip/hip_runtime.h>
#include <hip/hip_bf16.h>

#define N_NODES   50000
#define N_EDGES   500000
#define FDIM      128
#define N_CLASSES 32
#define N_GRAPHS  64

// ---------------------------------------------------------------------------
// Preprocessing: degree count, prefix scan over PADDED degrees (pad to x4),
// CSR fill + dummy self-edge padding (w=0).
// ---------------------------------------------------------------------------

__global__ void deg_kernel(const int* __restrict__ dst, int* __restrict__ deg, int E) {
    int e = blockIdx.x * blockDim.x + threadIdx.x;
    if (e < E) atomicAdd(&deg[dst[e]], 1);
}

__global__ void scan_partial(const int* __restrict__ deg, int* __restrict__ part,
                             float* __restrict__ dis, int n) {
    __shared__ int s[512];
    int t = threadIdx.x;
    int i = blockIdx.x * 512 + t;
    int d = (i < n) ? deg[i] : 0;
    if (i < n) dis[i] = rsqrtf((float)d + 1.0f);
    s[t] = (i < n) ? ((d + 3) & ~3) : 0;
    __syncthreads();
    for (int o = 256; o > 0; o >>= 1) {
        if (t < o) s[t] += s[t + o];
        __syncthreads();
    }
    if (t == 0) part[blockIdx.x] = s[0];
}

__global__ void scan_offsets(int* part, int nb) {
    if (blockIdx.x == 0 && threadIdx.x == 0) {
        int acc = 0;
        for (int i = 0; i < nb; i++) { int v = part[i]; part[i] = acc; acc += v; }
    }
}

__global__ void scan_final(const int* __restrict__ deg, const int* __restrict__ part,
                           int* __restrict__ rowptr, int n) {
    __shared__ int s[512];
    int t = threadIdx.x;
    int i = blockIdx.x * 512 + t;
    int v = (i < n) ? ((deg[i] + 3) & ~3) : 0;
    s[t] = v;
    __syncthreads();
    for (int o = 1; o < 512; o <<= 1) {
        int x = (t >= o) ? s[t - o] : 0;
        __syncthreads();
        s[t] += x;
        __syncthreads();
    }
    if (i < n) rowptr[i] = part[blockIdx.x] + s[t] - v;   // exclusive (padded)
}

__global__ void fill_csr(const int* __restrict__ src, const int* __restrict__ dst,
                         const int* __restrict__ rowptr, int* __restrict__ fill,
                         const float* __restrict__ dis,
                         int2* __restrict__ csr_sw, int E) {
    int e = blockIdx.x * blockDim.x + threadIdx.x;
    if (e >= E) return;
    int d = dst[e], s = src[e];
    int pos = rowptr[d] + atomicAdd(&fill[d], 1);
    float w = dis[s] * dis[d];
    csr_sw[pos] = make_int2(s, __float_as_int(w));
}

__global__ void pad_csr(const int* __restrict__ deg, const int* __restrict__ rowptr,
                        int2* __restrict__ csr_sw, int n) {
    int v = blockIdx.x * blockDim.x + threadIdx.x;
    if (v >= n) return;
    int d = deg[v], dp = (d + 3) & ~3;
    int base = rowptr[v];
    for (int i = d; i < dp; i++) csr_sw[base + i] = make_int2(v, 0);
}

// ---------------------------------------------------------------------------
// Fused GCN layer: OUT = relu( ((A + ns*I) H) W + b )
// Uses associativity: aggregate FIRST (raw h rows), then transform in-LDS.
// 256 threads = 4 waves; block owns 32 nodes.
//   Phase 1 (gather): each wave aggregates 8 nodes (float4/lane, 2 edges per
//     gather instruction across wave halves), writes transposed into xs.
//   Phase 2 (gemm): proven 4x4 micro-tile over K-chunks of 32, W staged in LDS.
// ---------------------------------------------------------------------------

#define PGATH(I, EBASE)                                                         \
    int2 p##I = sw[(EBASE) + 2 * (I) + half];                                   \
    float4 m##I = *(const float4*)(H + (size_t)p##I.x * FDIM + q * 4);

#define PFMA(I)                                                                 \
    {                                                                           \
        float w_ = __int_as_float(p##I.y);                                      \
        acc.x = fmaf(w_, m##I.x, acc.x);                                        \
        acc.y = fmaf(w_, m##I.y, acc.y);                                        \
        acc.z = fmaf(w_, m##I.z, acc.z);                                        \
        acc.w = fmaf(w_, m##I.w, acc.w);                                        \
    }

__global__ __launch_bounds__(256) void fused_layer(const float* __restrict__ H,
                                                   const float* __restrict__ W,
                                                   const float* __restrict__ bias,
                                                   float* __restrict__ OUT,
                                                   const int* __restrict__ rowptr,
                                                   const int* __restrict__ degi,
                                                   const int2* __restrict__ csr_sw,
                                                   const float* __restrict__ dis,
                                                   int n, int relu) {
    __shared__ __align__(16) float xs[FDIM][36];   // agg result, transposed [feat][node]
    __shared__ __align__(16) float ws[32][132];    // W K-chunk [k][col]
    int t = threadIdx.x;
    int lane = t & 63;
    int wv = t >> 6;        // wave 0..3
    int half = lane >> 5;   // which edge of the pair
    int q = lane & 31;      // feature quarter: features q*4 .. q*4+3
    int rowBase = blockIdx.x * 32;

    // ---- Phase 1: aggregate 8 nodes per wave ----
    for (int i = 0; i < 8; i++) {
        int r = wv * 8 + i;
        int v = rowBase + r;
        float4 acc = make_float4(0.f, 0.f, 0.f, 0.f);
        if (v < n) {
            const int2* sw = csr_sw + rowptr[v];
            int cnt = (degi[v] + 3) & ~3;   // padded, multiple of 4
            int e = 0;
            for (; e + 16 <= cnt; e += 16) {   // 8 instrs, 16 edges
                PGATH(0, e) PGATH(1, e) PGATH(2, e) PGATH(3, e)
                PGATH(4, e) PGATH(5, e) PGATH(6, e) PGATH(7, e)
                PFMA(0) PFMA(1) PFMA(2) PFMA(3) PFMA(4) PFMA(5) PFMA(6) PFMA(7)
            }
            if (e + 8 <= cnt) {
                PGATH(0, e) PGATH(1, e) PGATH(2, e) PGATH(3, e)
                PFMA(0) PFMA(1) PFMA(2) PFMA(3)
                e += 8;
            }
            if (e + 4 <= cnt) {
                PGATH(0, e) PGATH(1, e)
                PFMA(0) PFMA(1)
            }
            // merge the two halves
            acc.x += __shfl_xor(acc.x, 32);
            acc.y += __shfl_xor(acc.y, 32);
            acc.z += __shfl_xor(acc.z, 32);
            acc.w += __shfl_xor(acc.w, 32);
            // self-loop term ns*h_v
            float dv = dis[v];
            float ns = dv * dv;
            float4 hv = *(const float4*)(H + (size_t)v * FDIM + q * 4);
            acc.x = fmaf(ns, hv.x, acc.x);
            acc.y = fmaf(ns, hv.y, acc.y);
            acc.z = fmaf(ns, hv.z, acc.z);
            acc.w = fmaf(ns, hv.w, acc.w);
        }
        if (half == 0) {   // 32 lanes write the 128-feature row transposed
            xs[q * 4 + 0][r] = acc.x;
            xs[q * 4 + 1][r] = acc.y;
            xs[q * 4 + 2][r] = acc.z;
            xs[q * 4 + 3][r] = acc.w;
        }
    }

    // ---- Phase 2: (agg)W + b, 4x4 micro-tile ----
    int ti = t & 7;      // row group: rows ti*4 .. ti*4+3
    int tj = t >> 3;     // col group: cols tj*4 .. tj*4+3
    float acc2[4][4];
#pragma unroll
    for (int r = 0; r < 4; r++)
#pragma unroll
        for (int c = 0; c < 4; c++) acc2[r][c] = 0.f;

    for (int k0 = 0; k0 < 128; k0 += 32) {
        __syncthreads();   // first iter: covers xs writes; later: ws reuse
        {
            int c4 = t & 31, kr = t >> 5;
#pragma unroll
            for (int p = 0; p < 4; p++) {
                int k = kr + 8 * p;
                float4 v = *(const float4*)(W + (size_t)(k0 + k) * FDIM + c4 * 4);
                *(float4*)&ws[k][c4 * 4] = v;
            }
        }
        __syncthreads();
#pragma unroll 8
        for (int k = 0; k < 32; k++) {
            float4 a = *(const float4*)&xs[k0 + k][ti * 4];
            float4 b = *(const float4*)&ws[k][tj * 4];
            float ar[4] = {a.x, a.y, a.z, a.w};
            float br[4] = {b.x, b.y, b.z, b.w};
#pragma unroll
            for (int r = 0; r < 4; r++)
#pragma unroll
                for (int c = 0; c < 4; c++) acc2[r][c] = fmaf(ar[r], br[c], acc2[r][c]);
        }
    }

    float4 bb = *(const float4*)(bias + tj * 4);
#pragma unroll
    for (int rr = 0; rr < 4; rr++) {
        int grow = rowBase + ti * 4 + rr;
        if (grow < n) {
            float4 o;
            o.x = acc2[rr][0] + bb.x;
            o.y = acc2[rr][1] + bb.y;
            o.z = acc2[rr][2] + bb.z;
            o.w = acc2[rr][3] + bb.w;
            if (relu) {
                o.x = fmaxf(o.x, 0.f); o.y = fmaxf(o.y, 0.f);
                o.z = fmaxf(o.z, 0.f); o.w = fmaxf(o.w, 0.f);
            }
            *(float4*)(OUT + (size_t)grow * FDIM + tj * 4) = o;
        }
    }
}

// ---------------------------------------------------------------------------
// Pooling: batch[] is SORTED. Segmented reduce, one atomic per boundary.
// ---------------------------------------------------------------------------

#define POOL_BLOCKS 1024

__global__ __launch_bounds__(128) void pool_kernel(const float* __restrict__ H,
                                                   const int* __restrict__ batch,
                                                   float* __restrict__ psum,
                                                   float* __restrict__ pcnt, int n) {
    int t = threadIdx.x;
    int chunk = (n + POOL_BLOCKS - 1) / POOL_BLOCKS;
    int lo = blockIdx.x * chunk;
    int hi = lo + chunk; if (hi > n) hi = n;
    if (lo >= hi) return;

    float acc = 0.f;
    int cnt = 0;
    int curg = batch[lo];
    float hv = H[(size_t)lo * FDIM + t];
    int g = curg;
    for (int v = lo; v < hi; v++) {
        float hcur = hv;
        int gcur = g;
        if (v + 1 < hi) {
            hv = H[(size_t)(v + 1) * FDIM + t];
            g = batch[v + 1];
        }
        if (gcur != curg) {
            atomicAdd(&psum[curg * FDIM + t], acc);
            if (t == 0) atomicAdd(&pcnt[curg], (float)cnt);
            acc = 0.f; cnt = 0; curg = gcur;
        }
        acc += hcur;
        cnt++;
    }
    atomicAdd(&psum[curg * FDIM + t], acc);
    if (t == 0) atomicAdd(&pcnt[curg], (float)cnt);
}

__global__ void final_lin(const float* __restrict__ psum, const float* __restrict__ pcnt,
                          const float* __restrict__ Wl, const float* __restrict__ bl,
                          float* __restrict__ out) {
    int t = blockIdx.x * blockDim.x + threadIdx.x;
    if (t >= N_GRAPHS * N_CLASSES) return;
    int g = t >> 5, c = t & 31;
    float inv = 1.0f / fmaxf(pcnt[g], 1.0f);
    float s = 0.f;
    for (int k = 0; k < FDIM; k++) s = fmaf(psum[g * FDIM + k], Wl[k * N_CLASSES + c], s);
    out[t] = s * inv + bl[c];
}

// ---------------------------------------------------------------------------

static inline size_t align256(size_t x) { return (x + 255) & ~(size_t)255; }

extern "C" void kernel_launch(void* const* d_in, const int* in_sizes, int n_in,
                              void* d_out, int out_size, void* d_ws, size_t ws_size,
                              hipStream_t stream) {
    const float* x     = (const float*)d_in[0];
    const int*   ei    = (const int*)d_in[1];
    const int*   batch = (const int*)d_in[2];
    const float* Wls[5] = {(const float*)d_in[3], (const float*)d_in[5], (const float*)d_in[7],
                           (const float*)d_in[9], (const float*)d_in[11]};
    const float* bls[5] = {(const float*)d_in[4], (const float*)d_in[6], (const float*)d_in[8],
                           (const float*)d_in[10], (const float*)d_in[12]};
    const float* W_lin = (const float*)d_in[13];
    const float* b_lin = (const float*)d_in[14];
    float* out = (float*)d_out;

    const int N = N_NODES, E = N_EDGES;
    const int* src = ei;
    const int* dst = ei + E;

    // workspace layout: zeroed arrays (deg,fill,psum,pcnt) laid out contiguously
    char* p = (char*)d_ws;
    size_t off = 0;
    float* hA = (float*)(p + off); off = align256(off + (size_t)N * FDIM * 4);
    float* hB = (float*)(p + off); off = align256(off + (size_t)N * FDIM * 4);
    int2*  csr_sw = (int2*)(p + off); off = align256(off + ((size_t)E + 4 * N) * 8);
    float* dis = (float*)(p + off); off = align256(off + (size_t)N * 4);
    int*   rowptr = (int*)(p + off); off = align256(off + (size_t)N * 4);
    int*   part = (int*)(p + off); off = align256(off + 512);
    size_t zero_off = off;
    int*   deg = (int*)(p + off); off = align256(off + (size_t)N * 4);
    int*   fill = (int*)(p + off); off = align256(off + (size_t)N * 4);
    float* psum = (float*)(p + off); off = align256(off + (size_t)N_GRAPHS * FDIM * 4);
    float* pcnt = (float*)(p + off); off = align256(off + (size_t)N_GRAPHS * 4);
    size_t zero_bytes = off - zero_off;
    (void)ws_size; (void)n_in; (void)in_sizes; (void)out_size;

    hipMemsetAsync(p + zero_off, 0, zero_bytes, stream);

    // preprocessing
    deg_kernel<<<(E + 255) / 256, 256, 0, stream>>>(dst, deg, E);
    int nChunks = (N + 511) / 512;  // 98
    scan_partial<<<nChunks, 512, 0, stream>>>(deg, part, dis, N);
    scan_offsets<<<1, 64, 0, stream>>>(part, nChunks);
    scan_final<<<nChunks, 512, 0, stream>>>(deg, part, rowptr, N);
    fill_csr<<<(E + 255) / 256, 256, 0, stream>>>(src, dst, rowptr, fill, dis,
                                                  csr_sw, E);
    pad_csr<<<(N + 255) / 256, 256, 0, stream>>>(deg, rowptr, csr_sw, N);

    // 5 fused GCN layers: h_{l+1} = relu(((A+nsI) h_l) W_l + b_l)
    int fusedBlocks = (N + 31) / 32;   // 1563
    const float* cur = x;
    float* bufs[2] = {hA, hB};
    for (int l = 0; l < 5; l++) {
        float* dst_h = bufs[l & 1];
        int relu = (l < 4) ? 1 : 0;
        fused_layer<<<fusedBlocks, 256, 0, stream>>>(cur, Wls[l], bls[l], dst_h,
                                                     rowptr, deg, csr_sw, dis, N, relu);
        cur = dst_h;
    }

    // pooling + classifier (final h is hA: layers 0,2,4 wrote hA)
    pool_kernel<<<POOL_BLOCKS, 128, 0, stream>>>(hA, batch, psum, pcnt, N);
    final_lin<<<(N_GRAPHS * N_CLASSES + 255) / 256, 256, 0, stream>>>(psum, pcnt, W_lin,
                                                                      b_lin, out);
}